// Round 8
// baseline (92.221 us; speedup 1.0000x reference)
//
#include <hip/hip_runtime.h>

#define D    64
#define NROW 8192

typedef _Float16 f16x8 __attribute__((ext_vector_type(8)));
typedef float    f32x4 __attribute__((ext_vector_type(4)));

// ---------------------------------------------------------------------------
// Persistent pipelined RBF kernel.
// Grid = 512 blocks = exactly 2 blocks/CU (single co-resident round, no
// block turnover). Block b handles col-tile (b&63) and EIGHT row-tiles
// (rowbase = (b>>6)*1024). y tile staged in LDS ONCE (single barrier);
// then per row-tile, with NO barriers: prefetch next x-frags (raw f32,
// double-buffered regs) -> convert -> MFMA -> exp -> store. Stores of tile
// t drain under compute of tile t+1 -> continuous write stream instead of
// end-of-block bursts (theory: store-phase convoying caps write BW at
// 4 TB/s while fill achieves 7).
// Numerics/layouts identical to the R3-verified kernel.
// ---------------------------------------------------------------------------
__global__ __launch_bounds__(256, 2) void rbf_pipe(const float* __restrict__ x,
                                                   const float* __restrict__ y,
                                                   float* __restrict__ out) {
    __shared__ __align__(16) char YH[16384];   // f16[128 rows][64 d], swizzled
    __shared__ __align__(16) char YL[16384];
    __shared__ float Ysq0[128];
    __shared__ float Ysq1[128];

    const int t       = threadIdx.x;
    const int b       = blockIdx.x;
    const int col0    = (b & 63) * 128;        // y-col tile
    const int rowbase = (b >> 6) * 1024;       // 8 row-tiles of 128

    // ---- stage y tile once: hi/lo split + partial norms (R3-verified) ----
    {
        const int r    = t & 127;
        const int half = t >> 7;
        const int swz  = (r & 7) << 4;
        const float* yp = y + (size_t)(col0 + r) * D + half * 32;
        float ssq = 0.f;
#pragma unroll
        for (int it = 0; it < 4; ++it) {
            float4 b0 = *reinterpret_cast<const float4*>(yp + it * 8);
            float4 b1 = *reinterpret_cast<const float4*>(yp + it * 8 + 4);
            float v[8] = {b0.x, b0.y, b0.z, b0.w, b1.x, b1.y, b1.z, b1.w};
            f16x8 h, l;
#pragma unroll
            for (int j = 0; j < 8; ++j) {
                _Float16 hh = (_Float16)v[j];
                h[j] = hh;
                l[j] = (_Float16)(v[j] - (float)hh);
                ssq  = fmaf(v[j], v[j], ssq);
            }
            const int off = r * 128 + ((half * 64 + it * 16) ^ swz);
            *reinterpret_cast<f16x8*>(YH + off) = h;
            *reinterpret_cast<f16x8*>(YL + off) = l;
        }
        if (half == 0) Ysq0[r] = ssq; else Ysq1[r] = ssq;
    }
    __syncthreads();   // the ONLY barrier

    const int lane = t & 63;
    const int w    = t >> 6;
    const int l15  = lane & 15;
    const int lg   = lane >> 4;
    const int swzA = (l15 & 7) << 4;

    // raw x prefetch buffers: [i = row sub-tile][kh][half-of-8] float4
    float4 PA[2][2][2], PB[2][2][2];

    auto LOADX = [&](int rt, float4 (&P)[2][2][2]) {
#pragma unroll
        for (int i = 0; i < 2; ++i) {
            const float* xp = x + (size_t)(rowbase + rt * 128 + w * 32 + i * 16 + l15) * D + lg * 8;
            P[i][0][0] = *reinterpret_cast<const float4*>(xp);
            P[i][0][1] = *reinterpret_cast<const float4*>(xp + 4);
            P[i][1][0] = *reinterpret_cast<const float4*>(xp + 32);
            P[i][1][1] = *reinterpret_cast<const float4*>(xp + 36);
        }
    };

    auto TILE = [&](const float4 (&P)[2][2][2], int rt) {
        // ---- convert raw f32 -> f16 hi/lo frags + xsq (R3-verified) ------
        f16x8 xh[2][2], xl[2][2];
        float xsq[2];
#pragma unroll
        for (int i = 0; i < 2; ++i) {
            float s = 0.f;
#pragma unroll
            for (int kh = 0; kh < 2; ++kh) {
                float v[8] = {P[i][kh][0].x, P[i][kh][0].y, P[i][kh][0].z, P[i][kh][0].w,
                              P[i][kh][1].x, P[i][kh][1].y, P[i][kh][1].z, P[i][kh][1].w};
#pragma unroll
                for (int j = 0; j < 8; ++j) {
                    _Float16 hh = (_Float16)v[j];
                    xh[i][kh][j] = hh;
                    xl[i][kh][j] = (_Float16)(v[j] - (float)hh);
                    s = fmaf(v[j], v[j], s);
                }
            }
            s += __shfl_xor(s, 16);
            s += __shfl_xor(s, 32);
            xsq[i] = s;
        }

        // ---- MFMA (R3-verified swapped-operand structure) ----------------
        f32x4 acc[2][8];
#pragma unroll
        for (int i = 0; i < 2; ++i)
#pragma unroll
            for (int nt = 0; nt < 8; ++nt) acc[i][nt] = (f32x4){0.f, 0.f, 0.f, 0.f};

#pragma unroll
        for (int kh = 0; kh < 2; ++kh) {
            const int dsw = (kh * 64 + lg * 16) ^ swzA;
#pragma unroll
            for (int nt = 0; nt < 8; ++nt) {
                const int aoff = (nt * 16 + l15) * 128 + dsw;
                f16x8 yh = *reinterpret_cast<const f16x8*>(YH + aoff);
                f16x8 yl = *reinterpret_cast<const f16x8*>(YL + aoff);
                acc[0][nt] = __builtin_amdgcn_mfma_f32_16x16x32_f16(yh, xh[0][kh], acc[0][nt], 0, 0, 0);
                acc[1][nt] = __builtin_amdgcn_mfma_f32_16x16x32_f16(yh, xh[1][kh], acc[1][nt], 0, 0, 0);
                acc[0][nt] = __builtin_amdgcn_mfma_f32_16x16x32_f16(yl, xh[0][kh], acc[0][nt], 0, 0, 0);
                acc[1][nt] = __builtin_amdgcn_mfma_f32_16x16x32_f16(yl, xh[1][kh], acc[1][nt], 0, 0, 0);
                acc[0][nt] = __builtin_amdgcn_mfma_f32_16x16x32_f16(yh, xl[0][kh], acc[0][nt], 0, 0, 0);
                acc[1][nt] = __builtin_amdgcn_mfma_f32_16x16x32_f16(yh, xl[1][kh], acc[1][nt], 0, 0, 0);
            }
        }

        // ---- epilogue: dist^2 -> exp -> float4 stores (verified layout) --
#pragma unroll
        for (int nt = 0; nt < 8; ++nt) {
            const int c = nt * 16 + lg * 4;
            float4 p0 = *reinterpret_cast<const float4*>(&Ysq0[c]);
            float4 p1 = *reinterpret_cast<const float4*>(&Ysq1[c]);
            float ysqv[4] = {p0.x + p1.x, p0.y + p1.y, p0.z + p1.z, p0.w + p1.w};
#pragma unroll
            for (int i = 0; i < 2; ++i) {
                const int rowg = rowbase + rt * 128 + w * 32 + i * 16 + l15;
                float e[4];
#pragma unroll
                for (int r = 0; r < 4; ++r) {
                    float d2 = fmaf(-2.f, acc[i][nt][r], xsq[i] + ysqv[r]);
                    d2 = fmaxf(d2, 0.f);
                    e[r] = __expf(-d2);
                }
                *reinterpret_cast<float4*>(out + (size_t)rowg * NROW + col0 + c) =
                    make_float4(e[0], e[1], e[2], e[3]);
            }
        }
    };

    // ---- software-pipelined tile loop: prefetch t+1 before computing t ---
    LOADX(0, PA);
#pragma unroll
    for (int tp = 0; tp < 4; ++tp) {
        LOADX(2 * tp + 1, PB);
        TILE(PA, 2 * tp);
        if (tp < 3) LOADX(2 * tp + 2, PA);
        TILE(PB, 2 * tp + 1);
    }
}

extern "C" void kernel_launch(void* const* d_in, const int* in_sizes, int n_in,
                              void* d_out, int out_size, void* d_ws, size_t ws_size,
                              hipStream_t stream) {
    const float* x = (const float*)d_in[0];
    const float* y = (const float*)d_in[1];
    float* out = (float*)d_out;
    (void)d_ws; (void)ws_size;

    rbf_pipe<<<dim3(512), 256, 0, stream>>>(x, y, out);
}

// Round 9
// 83.411 us; speedup vs baseline: 1.1056x; 1.1056x over previous
//
#include <hip/hip_runtime.h>

#define D    64
#define NROW 8192

typedef _Float16 f16x8 __attribute__((ext_vector_type(8)));
typedef float    f32x4 __attribute__((ext_vector_type(4)));

// ---------------------------------------------------------------------------
// R3 kernel (67.2 us, verified) + ONE change: nontemporal epilogue stores.
// Theory: out (256 MB) == LLC size; write-allocate turns the LLC over every
// pass, evicting x/y -> tile reads miss to HBM (total ~536 MB ~= pin rate).
// NT stores bypass cache allocation -> inputs stay resident, writes stream
// at fill-kernel efficiency (~7 TB/s).
// ---------------------------------------------------------------------------
__global__ __launch_bounds__(256, 3) void rbf_fused(const float* __restrict__ x,
                                                    const float* __restrict__ y,
                                                    float* __restrict__ out) {
    __shared__ __align__(16) char YH[16384];   // f16[128 rows][64 d], swizzled
    __shared__ __align__(16) char YL[16384];
    __shared__ float Ysq0[128];
    __shared__ float Ysq1[128];

    const int t    = threadIdx.x;
    const int col0 = blockIdx.x * 128;   // y-col tile
    const int row0 = blockIdx.y * 128;   // x-row tile

    // ---- stage y tile: hi/lo split + partial squared norms ---------------
    {
        const int r    = t & 127;
        const int half = t >> 7;
        const int swz  = (r & 7) << 4;
        const float* yp = y + (size_t)(col0 + r) * D + half * 32;
        float ssq = 0.f;
#pragma unroll
        for (int it = 0; it < 4; ++it) {
            float4 b0 = *reinterpret_cast<const float4*>(yp + it * 8);
            float4 b1 = *reinterpret_cast<const float4*>(yp + it * 8 + 4);
            float v[8] = {b0.x, b0.y, b0.z, b0.w, b1.x, b1.y, b1.z, b1.w};
            f16x8 h, l;
#pragma unroll
            for (int j = 0; j < 8; ++j) {
                _Float16 hh = (_Float16)v[j];
                h[j] = hh;
                l[j] = (_Float16)(v[j] - (float)hh);
                ssq  = fmaf(v[j], v[j], ssq);
            }
            const int off = r * 128 + ((half * 64 + it * 16) ^ swz);
            *reinterpret_cast<f16x8*>(YH + off) = h;
            *reinterpret_cast<f16x8*>(YL + off) = l;
        }
        if (half == 0) Ysq0[r] = ssq; else Ysq1[r] = ssq;
    }

    // ---- x fragments direct from global, split in-register ---------------
    const int lane = t & 63;
    const int w    = t >> 6;
    const int l15  = lane & 15;
    const int lg   = lane >> 4;

    f16x8 xh[2][2], xl[2][2];
    float xsq[2];
#pragma unroll
    for (int i = 0; i < 2; ++i) {
        const float* xp = x + (size_t)(row0 + w * 32 + i * 16 + l15) * D + lg * 8;
        float s = 0.f;
#pragma unroll
        for (int kh = 0; kh < 2; ++kh) {
            float4 a0 = *reinterpret_cast<const float4*>(xp + kh * 32);
            float4 a1 = *reinterpret_cast<const float4*>(xp + kh * 32 + 4);
            float v[8] = {a0.x, a0.y, a0.z, a0.w, a1.x, a1.y, a1.z, a1.w};
#pragma unroll
            for (int j = 0; j < 8; ++j) {
                _Float16 hh = (_Float16)v[j];
                xh[i][kh][j] = hh;
                xl[i][kh][j] = (_Float16)(v[j] - (float)hh);
                s = fmaf(v[j], v[j], s);
            }
        }
        s += __shfl_xor(s, 16);
        s += __shfl_xor(s, 32);
        xsq[i] = s;
    }
    __syncthreads();

    // ---- MFMA main: A = y (LDS), B = x (reg); 96 MFMAs / wave ------------
    f32x4 acc[2][8];
#pragma unroll
    for (int i = 0; i < 2; ++i)
#pragma unroll
        for (int nt = 0; nt < 8; ++nt) acc[i][nt] = (f32x4){0.f, 0.f, 0.f, 0.f};

    const int swzA = (l15 & 7) << 4;
#pragma unroll
    for (int kh = 0; kh < 2; ++kh) {
        const int dsw = (kh * 64 + lg * 16) ^ swzA;
#pragma unroll
        for (int nt = 0; nt < 8; ++nt) {
            const int aoff = (nt * 16 + l15) * 128 + dsw;
            f16x8 yh = *reinterpret_cast<const f16x8*>(YH + aoff);
            f16x8 yl = *reinterpret_cast<const f16x8*>(YL + aoff);
            acc[0][nt] = __builtin_amdgcn_mfma_f32_16x16x32_f16(yh, xh[0][kh], acc[0][nt], 0, 0, 0);
            acc[1][nt] = __builtin_amdgcn_mfma_f32_16x16x32_f16(yh, xh[1][kh], acc[1][nt], 0, 0, 0);
            acc[0][nt] = __builtin_amdgcn_mfma_f32_16x16x32_f16(yl, xh[0][kh], acc[0][nt], 0, 0, 0);
            acc[1][nt] = __builtin_amdgcn_mfma_f32_16x16x32_f16(yl, xh[1][kh], acc[1][nt], 0, 0, 0);
            acc[0][nt] = __builtin_amdgcn_mfma_f32_16x16x32_f16(yh, xl[0][kh], acc[0][nt], 0, 0, 0);
            acc[1][nt] = __builtin_amdgcn_mfma_f32_16x16x32_f16(yh, xl[1][kh], acc[1][nt], 0, 0, 0);
        }
    }

    // ---- epilogue: dist^2 -> exp -> NONTEMPORAL float4 stores ------------
#pragma unroll
    for (int nt = 0; nt < 8; ++nt) {
        const int c = nt * 16 + lg * 4;
        float4 p0 = *reinterpret_cast<const float4*>(&Ysq0[c]);
        float4 p1 = *reinterpret_cast<const float4*>(&Ysq1[c]);
        float ysqv[4] = {p0.x + p1.x, p0.y + p1.y, p0.z + p1.z, p0.w + p1.w};
#pragma unroll
        for (int i = 0; i < 2; ++i) {
            const int rowg = row0 + w * 32 + i * 16 + l15;
            f32x4 e;
#pragma unroll
            for (int r = 0; r < 4; ++r) {
                float d2 = fmaf(-2.f, acc[i][nt][r], xsq[i] + ysqv[r]);
                d2 = fmaxf(d2, 0.f);
                e[r] = __expf(-d2);
            }
            __builtin_nontemporal_store(e,
                reinterpret_cast<f32x4*>(out + (size_t)rowg * NROW + col0 + c));
        }
    }
}

extern "C" void kernel_launch(void* const* d_in, const int* in_sizes, int n_in,
                              void* d_out, int out_size, void* d_ws, size_t ws_size,
                              hipStream_t stream) {
    const float* x = (const float*)d_in[0];
    const float* y = (const float*)d_in[1];
    float* out = (float*)d_out;
    (void)d_ws; (void)ws_size;

    rbf_fused<<<dim3(NROW / 128, NROW / 128), 256, 0, stream>>>(x, y, out);
}

// Round 10
// 67.235 us; speedup vs baseline: 1.3716x; 1.2406x over previous
//
#include <hip/hip_runtime.h>

#define D    64
#define NROW 8192

typedef _Float16 f16x8 __attribute__((ext_vector_type(8)));
typedef float    f32x4 __attribute__((ext_vector_type(4)));

// ---------------------------------------------------------------------------
// R6 kernel verbatim (transposed linear-store epilogue, verified correct,
// 70.1 us) with ONE change: nontemporal -> NORMAL stores.
// Theory T5: 64-B partial-line stores trigger L2 write-allocate reads of out
// lines (~268 MB hidden RFO traffic -> total ~536 MB ~ HBM pin rate). The
// LDS-transposed epilogue emits 256-B contiguous runs (full 128-B lines);
// with normal stores this should eliminate RFO. R9 showed NT stores
// themselves cost ~13-16 us, which masked this effect in R6.
// ---------------------------------------------------------------------------
__global__ __launch_bounds__(256, 3) void rbf_fused(const float* __restrict__ x,
                                                    const float* __restrict__ y,
                                                    float* __restrict__ out) {
    __shared__ __align__(16) char smem[32768];   // YH|YL, then f32 stage S
    __shared__ float Ysq0[128];
    __shared__ float Ysq1[128];
    char* const YH = smem;
    char* const YL = smem + 16384;

    const int t    = threadIdx.x;
    const int col0 = blockIdx.x * 128;   // y-col tile
    const int row0 = blockIdx.y * 128;   // x-row tile

    // ---- stage y tile: hi/lo split + partial squared norms ---------------
    {
        const int r    = t & 127;
        const int half = t >> 7;                 // d-halves 0..31 / 32..63
        const int swz  = (r & 7) << 4;
        const float* yp = y + (size_t)(col0 + r) * D + half * 32;
        float ssq = 0.f;
#pragma unroll
        for (int it = 0; it < 4; ++it) {
            float4 b0 = *reinterpret_cast<const float4*>(yp + it * 8);
            float4 b1 = *reinterpret_cast<const float4*>(yp + it * 8 + 4);
            float v[8] = {b0.x, b0.y, b0.z, b0.w, b1.x, b1.y, b1.z, b1.w};
            f16x8 h, l;
#pragma unroll
            for (int j = 0; j < 8; ++j) {
                _Float16 hh = (_Float16)v[j];
                h[j] = hh;
                l[j] = (_Float16)(v[j] - (float)hh);
                ssq  = fmaf(v[j], v[j], ssq);
            }
            const int off = r * 128 + ((half * 64 + it * 16) ^ swz);
            *reinterpret_cast<f16x8*>(YH + off) = h;
            *reinterpret_cast<f16x8*>(YL + off) = l;
        }
        if (half == 0) Ysq0[r] = ssq; else Ysq1[r] = ssq;
    }

    // ---- x fragments direct from global, split in-register ---------------
    const int lane = t & 63;
    const int w    = t >> 6;        // wave id -> x-row strip w*32
    const int l15  = lane & 15;
    const int lg   = lane >> 4;     // k-slot group

    f16x8 xh[2][2], xl[2][2];       // [row sub-tile][k half]
    float xsq[2];
#pragma unroll
    for (int i = 0; i < 2; ++i) {
        const float* xp = x + (size_t)(row0 + w * 32 + i * 16 + l15) * D + lg * 8;
        float s = 0.f;
#pragma unroll
        for (int kh = 0; kh < 2; ++kh) {
            float4 a0 = *reinterpret_cast<const float4*>(xp + kh * 32);
            float4 a1 = *reinterpret_cast<const float4*>(xp + kh * 32 + 4);
            float v[8] = {a0.x, a0.y, a0.z, a0.w, a1.x, a1.y, a1.z, a1.w};
#pragma unroll
            for (int j = 0; j < 8; ++j) {
                _Float16 hh = (_Float16)v[j];
                xh[i][kh][j] = hh;
                xl[i][kh][j] = (_Float16)(v[j] - (float)hh);
                s = fmaf(v[j], v[j], s);
            }
        }
        s += __shfl_xor(s, 16);
        s += __shfl_xor(s, 32);
        xsq[i] = s;
    }
    __syncthreads();

    // ---- MFMA main: A = y (LDS), B = x (reg); 96 MFMAs / wave ------------
    f32x4 acc[2][8];
#pragma unroll
    for (int i = 0; i < 2; ++i)
#pragma unroll
        for (int nt = 0; nt < 8; ++nt) acc[i][nt] = (f32x4){0.f, 0.f, 0.f, 0.f};

    const int swzA = (l15 & 7) << 4;
#pragma unroll
    for (int kh = 0; kh < 2; ++kh) {
        const int dsw = (kh * 64 + lg * 16) ^ swzA;
#pragma unroll
        for (int nt = 0; nt < 8; ++nt) {
            const int aoff = (nt * 16 + l15) * 128 + dsw;
            f16x8 yh = *reinterpret_cast<const f16x8*>(YH + aoff);
            f16x8 yl = *reinterpret_cast<const f16x8*>(YL + aoff);
            acc[0][nt] = __builtin_amdgcn_mfma_f32_16x16x32_f16(yh, xh[0][kh], acc[0][nt], 0, 0, 0);
            acc[1][nt] = __builtin_amdgcn_mfma_f32_16x16x32_f16(yh, xh[1][kh], acc[1][nt], 0, 0, 0);
            acc[0][nt] = __builtin_amdgcn_mfma_f32_16x16x32_f16(yl, xh[0][kh], acc[0][nt], 0, 0, 0);
            acc[1][nt] = __builtin_amdgcn_mfma_f32_16x16x32_f16(yl, xh[1][kh], acc[1][nt], 0, 0, 0);
            acc[0][nt] = __builtin_amdgcn_mfma_f32_16x16x32_f16(yh, xl[0][kh], acc[0][nt], 0, 0, 0);
            acc[1][nt] = __builtin_amdgcn_mfma_f32_16x16x32_f16(yh, xl[1][kh], acc[1][nt], 0, 0, 0);
        }
    }

    // ---- exp in place -----------------------------------------------------
#pragma unroll
    for (int nt = 0; nt < 8; ++nt) {
        const int c = nt * 16 + lg * 4;
        float4 p0 = *reinterpret_cast<const float4*>(&Ysq0[c]);
        float4 p1 = *reinterpret_cast<const float4*>(&Ysq1[c]);
        float ys[4] = {p0.x + p1.x, p0.y + p1.y, p0.z + p1.z, p0.w + p1.w};
#pragma unroll
        for (int i = 0; i < 2; ++i) {
#pragma unroll
            for (int r = 0; r < 4; ++r) {
                float d2 = fmaxf(fmaf(-2.f, acc[i][nt][r], xsq[i] + ys[r]), 0.f);
                acc[i][nt][r] = __expf(-d2);
            }
        }
    }
    __syncthreads();   // all waves done reading YH/YL (MFMA) before reuse

    // ---- transposed store: acc -> LDS f32 stage -> row-linear stores -----
    // S = f32[128 rows][64 cols] overlaid on YH|YL (32 KiB), wave-private
    // 32-row strips. Per store instruction: 4 rows x 256 B contiguous
    // (full 128-B lines) -> no partial-line write-allocate windows.
    char* const S = smem;
#pragma unroll
    for (int p = 0; p < 2; ++p) {          // col halves 0..63 / 64..127
#pragma unroll
        for (int k = 0; k < 4; ++k) {      // nt = p*4 + k
#pragma unroll
            for (int i = 0; i < 2; ++i) {
                const int row = w * 32 + i * 16 + l15;
                const int off = row * 256 + ((k * 64 + lg * 16) ^ ((row & 15) << 4));
                *reinterpret_cast<f32x4*>(S + off) = acc[i][p * 4 + k];
            }
        }
#pragma unroll
        for (int it = 0; it < 8; ++it) {
            const int rloc = w * 32 + it * 4 + (lane >> 4);
            const int off  = rloc * 256 + ((l15 * 16) ^ ((rloc & 15) << 4));
            f32x4 v = *reinterpret_cast<const f32x4*>(S + off);
            *reinterpret_cast<f32x4*>(out + (size_t)(row0 + rloc) * NROW
                                          + col0 + p * 64 + l15 * 4) = v;
        }
    }
}

extern "C" void kernel_launch(void* const* d_in, const int* in_sizes, int n_in,
                              void* d_out, int out_size, void* d_ws, size_t ws_size,
                              hipStream_t stream) {
    const float* x = (const float*)d_in[0];
    const float* y = (const float*)d_in[1];
    float* out = (float*)d_out;
    (void)d_ws; (void)ws_size;

    rbf_fused<<<dim3(NROW / 128, NROW / 128), 256, 0, stream>>>(x, y, out);
}